// Round 1
// baseline (45.689 us; speedup 1.0000x reference)
//
#include <hip/hip_runtime.h>

// Predict_Vectors_Down:
//   input  [2, 8, 128, 128, 4] fp32  -> flat [T=65536, 16]   (raw reshape)
//   weights[2, 8, 4096, 2,2, 8,8, 4] -> flat [T=65536, 4(yx), 64(oc), 4(i)]
//   out    [2, 8, 4096, 8, 8]        -> flat [T=65536, 64(oc)]
// out[t, l] = sum_{yx, i} W[t, yx, l, i] * X[t, yx, i]
//
// Memory-bound: 512 MiB weights read once. One wave per tile; lane l owns
// output element l. Per (yx): lane reads float4 W[t,yx,l,0:4] -> 64 lanes
// cover 1 KiB contiguous (fully coalesced). X block (16 floats) is
// wave-uniform -> broadcast loads. Store: 64 lanes x 4B = 256B contiguous.

constexpr int TILES = 16 * 4096;  // B*M * P = 65536

__global__ __launch_bounds__(256) void pvd_kernel(
    const float* __restrict__ x,      // [TILES, 16]
    const float4* __restrict__ w,     // [TILES, 256] float4s (= [T,4,64] of f4)
    float* __restrict__ out)          // [TILES, 64]
{
    const int wave = (int)((blockIdx.x * blockDim.x + threadIdx.x) >> 6);
    const int lane = threadIdx.x & 63;
    if (wave >= TILES) return;

    const float4* __restrict__ xb =
        reinterpret_cast<const float4*>(x + (size_t)wave * 16);
    const float4 x0 = xb[0];
    const float4 x1 = xb[1];
    const float4 x2 = xb[2];
    const float4 x3 = xb[3];

    const float4* __restrict__ wb = w + (size_t)wave * 256 + lane;
    const float4 w0 = wb[0];
    const float4 w1 = wb[64];
    const float4 w2 = wb[128];
    const float4 w3 = wb[192];

    float acc;
    acc  = w0.x * x0.x + w0.y * x0.y + w0.z * x0.z + w0.w * x0.w;
    acc += w1.x * x1.x + w1.y * x1.y + w1.z * x1.z + w1.w * x1.w;
    acc += w2.x * x2.x + w2.y * x2.y + w2.z * x2.z + w2.w * x2.w;
    acc += w3.x * x3.x + w3.y * x3.y + w3.z * x3.z + w3.w * x3.w;

    out[(size_t)wave * 64 + lane] = acc;
}

extern "C" void kernel_launch(void* const* d_in, const int* in_sizes, int n_in,
                              void* d_out, int out_size, void* d_ws, size_t ws_size,
                              hipStream_t stream) {
    const float*  x = (const float*)d_in[0];
    const float4* w = (const float4*)d_in[1];
    float* out = (float*)d_out;

    // 4 waves (one tile each) per 256-thread block.
    const int blocks = TILES / 4;  // 16384
    pvd_kernel<<<blocks, 256, 0, stream>>>(x, w, out);
}